// Round 12
// baseline (1015.515 us; speedup 1.0000x reference)
//
#include <hip/hip_runtime.h>
#include <math.h>

#define T_TOK 8192
#define DDIM  1024
#define HDIM  4096
#define NEXP  8
#define BM    128                     /* row tile */
#define BN    128                     /* col tile */
#define BK    64                      /* shorts per K-tile */
#define MAXROWS (T_TOK*2 + NEXP*BM)   /* 17408 */
#define MAXTILES (MAXROWS/BM)         /* 136 */
#define NCH   4                       /* pipeline chunks */
#define CS    (MAXTILES/NCH)          /* 34 tiles per chunk */

typedef __attribute__((ext_vector_type(8))) short short8;
typedef __attribute__((ext_vector_type(4))) short short4v;
typedef __attribute__((ext_vector_type(4))) float f32x4;

typedef const __attribute__((address_space(1))) unsigned int* gp1_t;
typedef __attribute__((address_space(3))) unsigned int* lp3_t;

__device__ __forceinline__ void gld16(const void* g, void* l) {
  __builtin_amdgcn_global_load_lds((gp1_t)g, (lp3_t)l, 16, 0, 0);
}

__device__ __forceinline__ short f2bf(float f) {
  unsigned u = __float_as_uint(f);
  u += 0x7fffu + ((u >> 16) & 1u);   // RNE
  return (short)(u >> 16);
}

// ---------------- weight transpose + fp32->bf16: wt[e][c][r] = w[e][r][c] ----------------
__global__ __launch_bounds__(256) void k_tr(const float* __restrict__ w,
                                            short* __restrict__ wt, int R, int C) {
  __shared__ float sl[64][65];
  int e = blockIdx.z;
  const float* W = w + (size_t)e * R * C;
  short* O = wt + (size_t)e * R * C;
  int c0 = blockIdx.x * 64, r0 = blockIdx.y * 64;
  int t = threadIdx.x;
  int lr = t >> 4, lc4 = (t & 15) * 4;
#pragma unroll
  for (int i = 0; i < 4; i++) {
    float4 v = *(const float4*)&W[(size_t)(r0 + lr + i * 16) * C + c0 + lc4];
    sl[lr + i * 16][lc4 + 0] = v.x;
    sl[lr + i * 16][lc4 + 1] = v.y;
    sl[lr + i * 16][lc4 + 2] = v.z;
    sl[lr + i * 16][lc4 + 3] = v.w;
  }
  __syncthreads();
#pragma unroll
  for (int i = 0; i < 4; i++) {
    int oc = lr + i * 16;
    short4v s;
#pragma unroll
    for (int j = 0; j < 4; j++) s[j] = f2bf(sl[lc4 + j][oc]);
    *(short4v*)&O[(size_t)(c0 + oc) * R + r0 + lc4] = s;
  }
}

// ---------------- gating (fp32 x, exact top-k) + fused x->bf16 convert ----------------
__global__ __launch_bounds__(256) void k_gate(const float* __restrict__ x,
    const float* __restrict__ gw, const float* __restrict__ gb,
    int2* __restrict__ toke, float2* __restrict__ tokw, int* __restrict__ cnt,
    short* __restrict__ xb) {
  __shared__ float sg[NEXP * DDIM];
  for (int i = threadIdx.x; i < NEXP * DDIM; i += 256) {
    int e = i >> 10, d = i & (DDIM - 1);
    sg[i] = gw[d * NEXP + e];
  }
  __syncthreads();
  int wave = threadIdx.x >> 6, lane = threadIdx.x & 63;
  int tok0 = blockIdx.x * 32;
  for (int tt = wave; tt < 32; tt += 4) {
    int tok = tok0 + tt;
    float p[NEXP];
#pragma unroll
    for (int e = 0; e < NEXP; e++) p[e] = 0.f;
#pragma unroll
    for (int c = 0; c < 4; c++) {
      int d = c * 256 + lane * 4;
      float4 xv = *(const float4*)&x[(size_t)tok * DDIM + d];
      short4v sv;                           // fused xb write (each elem covered once)
      sv[0] = f2bf(xv.x); sv[1] = f2bf(xv.y); sv[2] = f2bf(xv.z); sv[3] = f2bf(xv.w);
      *(short4v*)&xb[(size_t)tok * DDIM + d] = sv;
#pragma unroll
      for (int e = 0; e < NEXP; e++) {
        float4 g = *(const float4*)&sg[e * DDIM + d];
        p[e] += xv.x * g.x + xv.y * g.y + xv.z * g.z + xv.w * g.w;
      }
    }
#pragma unroll
    for (int off = 32; off; off >>= 1)
#pragma unroll
      for (int e = 0; e < NEXP; e++) p[e] += __shfl_xor(p[e], off);
    if (lane == 0) {
      float l[NEXP];
#pragma unroll
      for (int e = 0; e < NEXP; e++) l[e] = p[e] + gb[e];
      int i0 = 0;
#pragma unroll
      for (int e = 1; e < NEXP; e++) if (l[e] > l[i0]) i0 = e;
      int i1 = (i0 == 0) ? 1 : 0;
#pragma unroll
      for (int e = 0; e < NEXP; e++) if (e != i0 && l[e] > l[i1]) i1 = e;
      float ex = expf(l[i1] - l[i0]);
      float w0 = 1.f / (1.f + ex);
      toke[tok] = make_int2(i0, i1);
      tokw[tok] = make_float2(w0, 1.f - w0);
      atomicAdd(&cnt[i0], 1);
      atomicAdd(&cnt[i1], 1);
    }
  }
}

// ---------------- routing plan (64 threads) ----------------
__global__ void k_plan(const int* __restrict__ cnt, int* __restrict__ pbase,
                       int* __restrict__ texp) {
  int t = threadIdx.x;
  int b[NEXP + 1]; b[0] = 0;
#pragma unroll
  for (int e = 0; e < NEXP; e++) {
    int pc = (cnt[e] + BM - 1) & ~(BM - 1);
    b[e + 1] = b[e] + pc;
  }
  if (t < NEXP) pbase[t] = b[t];
  for (int i = t; i < MAXTILES; i += 64) {
    int r0 = i * BM, ee = -1;
#pragma unroll
    for (int e = 0; e < NEXP; e++) if (r0 >= b[e] && r0 < b[e + 1]) ee = e;
    texp[i] = ee;
  }
}

__global__ __launch_bounds__(256) void k_scatter(const int2* __restrict__ toke,
    const float2* __restrict__ tokw, const int* __restrict__ pbase,
    int* __restrict__ fill, int* __restrict__ rtok, float* __restrict__ rwgt) {
  int tok = blockIdx.x * 256 + threadIdx.x;
  if (tok >= T_TOK) return;
  int2 te = toke[tok];
  float2 tw = tokw[tok];
  int s0 = atomicAdd(&fill[te.x], 1);
  rtok[pbase[te.x] + s0] = tok; rwgt[pbase[te.x] + s0] = tw.x;
  int s1 = atomicAdd(&fill[te.y], 1);
  rtok[pbase[te.y] + s1] = tok; rwgt[pbase[te.y] + s1] = tw.y;
}

// ============== 128x128-tile grouped GEMM bodies (round-10 proven structure) =======
// 4 blocks/CU (acc[4][4]=64 AGPR, launch_bounds(256,4), 32 KiB LDS), XOR-8 swizzle
// (0 conflicts), simple STAGE->vmcnt(0)->barrier->MFMA->barrier loop.

#define STG(ko) { \
  gld16(sA[0] + (ko), &AL[(0 * 32 + wid * 8) * BK]); \
  gld16(sA[1] + (ko), &AL[(1 * 32 + wid * 8) * BK]); \
  gld16(sA[2] + (ko), &AL[(2 * 32 + wid * 8) * BK]); \
  gld16(sA[3] + (ko), &AL[(3 * 32 + wid * 8) * BK]); \
  gld16(sB[0] + (ko), &BL[(0 * 32 + wid * 8) * BK]); \
  gld16(sB[1] + (ko), &BL[(1 * 32 + wid * 8) * BK]); \
  gld16(sB[2] + (ko), &BL[(2 * 32 + wid * 8) * BK]); \
  gld16(sB[3] + (ko), &BL[(3 * 32 + wid * 8) * BK]); }

#define MFMA_TILE { \
  __builtin_amdgcn_s_setprio(1); \
  _Pragma("unroll") \
  for (int s = 0; s < 2; ++s) { \
    int xo = ((s * 4 + kg) ^ x7) << 3; \
    short8 af[4], bg[4]; \
    _Pragma("unroll") \
    for (int i = 0; i < 4; i++) af[i] = *(short8*)&AL[(wm + i * 16 + lr) * BK + xo]; \
    _Pragma("unroll") \
    for (int j = 0; j < 4; j++) bg[j] = *(short8*)&BL[(wn + j * 16 + lr) * BK + xo]; \
    _Pragma("unroll") \
    for (int i = 0; i < 4; i++) \
    _Pragma("unroll") \
    for (int j = 0; j < 4; j++) \
      acc[i][j] = __builtin_amdgcn_mfma_f32_16x16x32_bf16(af[i], bg[j], acc[i][j], 0, 0, 0); \
  } \
  __builtin_amdgcn_s_setprio(0); }

#define GEMM_LOOP(NKv) \
  for (int kt = 0; kt < (NKv); ++kt) { \
    STG(kt * BK); \
    asm volatile("s_waitcnt vmcnt(0)" ::: "memory"); \
    __syncthreads(); \
    MFMA_TILE; \
    __syncthreads(); \
  }

// ---- stage 1 body: h = gelu(x @ w1[e] + b1[e]) for tile tm, cols [n0,n0+128) ----
__device__ __forceinline__ void ffn1_body(int tm, int n0, short* LDSBUF,
    const short* __restrict__ xb, const short* __restrict__ w1t,
    const float* __restrict__ b1, const int* __restrict__ rtok,
    const int* __restrict__ texp, int hbase, short* __restrict__ hbuf) {
  int e = texp[tm];
  if (e < 0) return;
  const short* W = w1t + (size_t)e * HDIM * DDIM;
  short* AL = LDSBUF;
  short* BL = LDSBUF + BM * BK;
  int t = threadIdx.x, wid = t >> 6, lane = t & 63;
  int sr8 = lane >> 3, slot = lane & 7;
  int swz = (slot ^ sr8) * 8;
  const short* sA[4]; const short* sB[4];
#pragma unroll
  for (int i = 0; i < 4; i++) {
    int r = i * 32 + wid * 8 + sr8;
    int tok = rtok[tm * BM + r]; if (tok < 0) tok = 0;   // pads read row0 (dropped in ffn2)
    sA[i] = xb + (size_t)tok * DDIM + swz;
    sB[i] = W + (size_t)(n0 + r) * DDIM + swz;
  }
  f32x4 acc[4][4];
#pragma unroll
  for (int i = 0; i < 4; i++)
#pragma unroll
    for (int j = 0; j < 4; j++) acc[i][j] = (f32x4){0.f, 0.f, 0.f, 0.f};
  int wm = (wid >> 1) * 64, wn = (wid & 1) * 64;
  int lr = lane & 15, kg = lane >> 4, x7 = lr & 7;

  GEMM_LOOP(DDIM / BK)   // 16

  // LDS-staged vectorized epilogue (wave-private [32][68] region)
  short* SB = LDSBUF + wid * (32 * 68);
#pragma unroll
  for (int p = 0; p < 2; ++p) {
#pragma unroll
    for (int i2 = 0; i2 < 2; ++i2) {
      int i = p * 2 + i2;
#pragma unroll
      for (int j = 0; j < 4; ++j) {
        int col = j * 16 + lr;
        float bias = b1[e * HDIM + n0 + wn + col];
#pragma unroll
        for (int r = 0; r < 4; ++r) {
          float v = acc[i][j][r] + bias;
          v = 0.5f * v * (1.f + erff(v * 0.70710678118f));
          SB[(i2 * 16 + kg * 4 + r) * 68 + col] = f2bf(v);
        }
      }
    }
    int lrow = lane >> 1, c0 = (lane & 1) * 32;
    size_t grow = (size_t)((tm - hbase) * BM + wm + p * 32 + lrow);
#pragma unroll
    for (int s = 0; s < 4; ++s) {
      short8 v = *(short8*)&SB[lrow * 68 + c0 + s * 8];
      *(short8*)&hbuf[grow * HDIM + n0 + wn + c0 + s * 8] = v;
    }
  }
}

// ---- stage 2 body: out[tok] += wgt * (h @ w2[e] + b2[e]), optional split-K ----
__device__ __forceinline__ void ffn2_body(int tm, int n0, int kc, int KS,
    short* LDSBUF, const short* __restrict__ hbuf, const short* __restrict__ w2t,
    const float* __restrict__ b2, const int* __restrict__ rtok,
    const float* __restrict__ rwgt, const int* __restrict__ texp, int hbase,
    float* __restrict__ out) {
  int e = texp[tm];
  if (e < 0) return;
  const short* W = w2t + (size_t)e * DDIM * HDIM;
  short* AL = LDSBUF;
  short* BL = LDSBUF + BM * BK;
  int t = threadIdx.x, wid = t >> 6, lane = t & 63;
  int sr8 = lane >> 3, slot = lane & 7;
  int swz = (slot ^ sr8) * 8;
  const int NK = HDIM / BK / KS;
  int kbase = kc * NK * BK;
  const short* sA[4]; const short* sB[4];
#pragma unroll
  for (int i = 0; i < 4; i++) {
    int r = i * 32 + wid * 8 + sr8;
    sA[i] = hbuf + (size_t)((tm - hbase) * BM + r) * HDIM + kbase + swz;
    sB[i] = W + (size_t)(n0 + r) * HDIM + kbase + swz;
  }
  f32x4 acc[4][4];
#pragma unroll
  for (int i = 0; i < 4; i++)
#pragma unroll
    for (int j = 0; j < 4; j++) acc[i][j] = (f32x4){0.f, 0.f, 0.f, 0.f};
  int wm = (wid >> 1) * 64, wn = (wid & 1) * 64;
  int lr = lane & 15, kg = lane >> 4, x7 = lr & 7;

  GEMM_LOOP(NK)

#pragma unroll
  for (int j = 0; j < 4; j++) {
    int gcol = n0 + wn + j * 16 + lr;
    float bias = (kc == 0) ? b2[e * DDIM + gcol] : 0.f;
#pragma unroll
    for (int i = 0; i < 4; i++) {
      int rl = wm + i * 16 + kg * 4;
#pragma unroll
      for (int r = 0; r < 4; r++) {
        int grow = tm * BM + rl + r;
        int tok = rtok[grow];
        if (tok >= 0) {
          float v = (acc[i][j][r] + bias) * rwgt[grow];
          atomicAdd(&out[(size_t)tok * DDIM + gcol], v);
        }
      }
    }
  }
}

// ---------------- wrappers ----------------
// grid (32, nt): x = n0 (fast dim, round-10 proven order)
__global__ __launch_bounds__(256, 4) void k_ffn1(const short* __restrict__ xb,
    const short* __restrict__ w1t, const float* __restrict__ b1,
    const int* __restrict__ rtok, const int* __restrict__ texp,
    int tile0, int hbase, short* __restrict__ hbuf) {
  __shared__ short LDSBUF[2 * BM * BK];
  ffn1_body(tile0 + blockIdx.y, blockIdx.x * BN, LDSBUF, xb, w1t, b1, rtok, texp,
            hbase, hbuf);
}

// grid (8, nt, KS): x = n0 fast, z = split-K chunk
__global__ __launch_bounds__(256, 4) void k_ffn2(const short* __restrict__ hbuf,
    const short* __restrict__ w2t, const float* __restrict__ b2,
    const int* __restrict__ rtok, const float* __restrict__ rwgt,
    const int* __restrict__ texp, int tile0, int hbase, float* __restrict__ out) {
  __shared__ short LDSBUF[2 * BM * BK];
  ffn2_body(tile0 + blockIdx.y, blockIdx.x * BN, blockIdx.z, gridDim.z, LDSBUF,
            hbuf, w2t, b2, rtok, rwgt, texp, hbase, out);
}

// mixed launch: N2 ffn2 blocks (chunk c, read slot) + N1 ffn1 blocks (chunk c+1,
// write slot), Bresenham-interleaved so both types co-reside on every CU.
__global__ __launch_bounds__(256, 4) void k_mix(const short* __restrict__ xb,
    const short* __restrict__ w1t, const float* __restrict__ b1,
    const short* __restrict__ hbr, int t2lo, int hbase2,
    short* __restrict__ hbw, int t1lo, int hbase1,
    const short* __restrict__ w2t, const float* __restrict__ b2,
    const int* __restrict__ rtok, const float* __restrict__ rwgt,
    const int* __restrict__ texp, float* __restrict__ out, int N1, int N2) {
  __shared__ short LDSBUF[2 * BM * BK];
  int bx = blockIdx.x, N = N1 + N2;
  int i2  = (int)(((long long)bx * N2) / N);
  int i2n = (int)(((long long)(bx + 1) * N2) / N);
  if (i2n > i2) {
    ffn2_body(t2lo + (i2 >> 3), (i2 & 7) * BN, 0, 1, LDSBUF, hbr, w2t, b2,
              rtok, rwgt, texp, hbase2, out);
  } else {
    int i1 = bx - i2;
    ffn1_body(t1lo + (i1 >> 5), (i1 & 31) * BN, LDSBUF, xb, w1t, b1, rtok, texp,
              hbase1, hbw);
  }
}

extern "C" void kernel_launch(void* const* d_in, const int* in_sizes, int n_in,
                              void* d_out, int out_size, void* d_ws, size_t ws_size,
                              hipStream_t stream) {
  const float* x  = (const float*)d_in[0];
  const float* gw = (const float*)d_in[1];
  const float* gb = (const float*)d_in[2];
  const float* w1 = (const float*)d_in[3];
  const float* b1 = (const float*)d_in[4];
  const float* w2 = (const float*)d_in[5];
  const float* b2 = (const float*)d_in[6];
  float* out = (float*)d_out;
  char* ws = (char*)d_ws;

  // ws layout: 1MB header | w1t 67.1MB | w2t 67.1MB | xb 16.8MB | hbuf ring
  int*    cnt   = (int*)(ws + 0);
  int*    fill  = (int*)(ws + 32);
  int*    pbase = (int*)(ws + 64);
  int*    texp  = (int*)(ws + 128);
  int*    rtok  = (int*)(ws + 1024);
  float*  rwgt  = (float*)(ws + 1024 + (size_t)MAXROWS * 4);
  int2*   toke  = (int2*)(ws + 1024 + (size_t)MAXROWS * 8);
  float2* tokw  = (float2*)(ws + 1024 + (size_t)MAXROWS * 8 + (size_t)T_TOK * 8);
  size_t wbytes = (size_t)NEXP * DDIM * HDIM * 2;
  short*  w1t   = (short*)(ws + (1 << 20));
  short*  w2t   = (short*)(ws + (1 << 20) + wbytes);
  short*  xb    = (short*)(ws + (1 << 20) + 2 * wbytes);
  size_t hoff   = (1 << 20) + 2 * wbytes + (size_t)T_TOK * DDIM * 2;
  short*  hbuf  = (short*)(ws + hoff);
  size_t hcap   = ws_size > hoff ? ws_size - hoff : 0;

  hipMemsetAsync(d_out, 0, (size_t)T_TOK * DDIM * 4, stream);
  hipMemsetAsync(ws, 0, 128, stream);
  hipMemsetAsync(rtok, 0xFF, (size_t)MAXROWS * 4, stream);

  k_tr<<<dim3(HDIM / 64, DDIM / 64, NEXP), 256, 0, stream>>>(w1, w1t, DDIM, HDIM);
  k_tr<<<dim3(DDIM / 64, HDIM / 64, NEXP), 256, 0, stream>>>(w2, w2t, HDIM, DDIM);
  k_gate<<<256, 256, 0, stream>>>(x, gw, gb, toke, tokw, cnt, xb);
  k_plan<<<1, 64, 0, stream>>>(cnt, pbase, texp);
  k_scatter<<<T_TOK / 256, 256, 0, stream>>>(toke, tokw, pbase, fill, rtok, rwgt);

  size_t tshorts = (size_t)BM * HDIM;          // shorts per tile (1 MB)
  if (hcap >= 2 * (size_t)CS * tshorts * 2) {
    // pipelined path: ffn1(c0) | mix(ffn2 c, ffn1 c+1) x3 | ffn2(c3, split-K=4)
    k_ffn1<<<dim3(HDIM / BN, CS), 256, 0, stream>>>(xb, w1t, b1, rtok, texp,
                                                    0, 0, hbuf);
    for (int c = 0; c + 1 < NCH; ++c) {
      const short* hr = hbuf + (size_t)(c & 1) * CS * tshorts;
      short*       hw = hbuf + (size_t)((c + 1) & 1) * CS * tshorts;
      int N1 = (HDIM / BN) * CS, N2 = (DDIM / BN) * CS;
      k_mix<<<N1 + N2, 256, 0, stream>>>(xb, w1t, b1,
          hr, c * CS, c * CS, hw, (c + 1) * CS, (c + 1) * CS,
          w2t, b2, rtok, rwgt, texp, out, N1, N2);
    }
    k_ffn2<<<dim3(DDIM / BN, CS, 4), 256, 0, stream>>>(
        hbuf + (size_t)((NCH - 1) & 1) * CS * tshorts, w2t, b2, rtok, rwgt, texp,
        (NCH - 1) * CS, (NCH - 1) * CS, out);
  } else {
    // fallback: sequential chunked (round-10 behavior)
    int tpc = (int)(hcap / (tshorts * 2));
    if (tpc < 1) return;
    if (tpc > MAXTILES) tpc = MAXTILES;
    for (int base = 0; base < MAXTILES; base += tpc) {
      int nt = MAXTILES - base;
      if (nt > tpc) nt = tpc;
      k_ffn1<<<dim3(HDIM / BN, nt), 256, 0, stream>>>(xb, w1t, b1, rtok, texp,
                                                      base, base, hbuf);
      k_ffn2<<<dim3(DDIM / BN, nt, 2), 256, 0, stream>>>(hbuf, w2t, b2, rtok, rwgt,
                                                         texp, base, base, out);
    }
  }
}

// Round 13
// 828.534 us; speedup vs baseline: 1.2257x; 1.2257x over previous
//
#include <hip/hip_runtime.h>
#include <math.h>

#define T_TOK 8192
#define DDIM  1024
#define HDIM  4096
#define NEXP  8
#define BM    128                     /* row tile */
#define BN    128                     /* col tile */
#define BK    64                      /* shorts per K-tile */
#define MAXROWS (T_TOK*2 + NEXP*BM)   /* 17408 */
#define MAXTILES (MAXROWS/BM)         /* 136 */
#define KS2   2                       /* split-K factor for ffn2 */

typedef __attribute__((ext_vector_type(8))) short short8;
typedef __attribute__((ext_vector_type(4))) short short4v;
typedef __attribute__((ext_vector_type(4))) float f32x4;

typedef const __attribute__((address_space(1))) unsigned int* gp1_t;
typedef __attribute__((address_space(3))) unsigned int* lp3_t;

__device__ __forceinline__ void gld16(const void* g, void* l) {
  __builtin_amdgcn_global_load_lds((gp1_t)g, (lp3_t)l, 16, 0, 0);
}

__device__ __forceinline__ short f2bf(float f) {
  unsigned u = __float_as_uint(f);
  u += 0x7fffu + ((u >> 16) & 1u);   // RNE
  return (short)(u >> 16);
}

// ---------------- weight transpose + fp32->bf16: wt[e][c][r] = w[e][r][c] ----------------
__global__ __launch_bounds__(256) void k_tr(const float* __restrict__ w,
                                            short* __restrict__ wt, int R, int C) {
  __shared__ float sl[64][65];
  int e = blockIdx.z;
  const float* W = w + (size_t)e * R * C;
  short* O = wt + (size_t)e * R * C;
  int c0 = blockIdx.x * 64, r0 = blockIdx.y * 64;
  int t = threadIdx.x;
  int lr = t >> 4, lc4 = (t & 15) * 4;
#pragma unroll
  for (int i = 0; i < 4; i++) {
    float4 v = *(const float4*)&W[(size_t)(r0 + lr + i * 16) * C + c0 + lc4];
    sl[lr + i * 16][lc4 + 0] = v.x;
    sl[lr + i * 16][lc4 + 1] = v.y;
    sl[lr + i * 16][lc4 + 2] = v.z;
    sl[lr + i * 16][lc4 + 3] = v.w;
  }
  __syncthreads();
#pragma unroll
  for (int i = 0; i < 4; i++) {
    int oc = lr + i * 16;
    short4v s;
#pragma unroll
    for (int j = 0; j < 4; j++) s[j] = f2bf(sl[lc4 + j][oc]);
    *(short4v*)&O[(size_t)(c0 + oc) * R + r0 + lc4] = s;
  }
}

// ---------------- gating: high-parallelism (1024 blocks), fused x->bf16 ----------------
// sg staged coalesced: float4 of gw covers 4 experts of one d -> transposed LDS write.
__global__ __launch_bounds__(256) void k_gate(const float* __restrict__ x,
    const float* __restrict__ gw, const float* __restrict__ gb,
    int2* __restrict__ toke, float2* __restrict__ tokw, int* __restrict__ cnt,
    short* __restrict__ xb) {
  __shared__ float sg[NEXP * DDIM];   // [e][d], 32 KB
  int t = threadIdx.x;
#pragma unroll
  for (int it = 0; it < 8; ++it) {
    int l0 = (it * 256 + t) * 4;               // linear gw index (d*8+e)
    float4 v = *(const float4*)&gw[l0];
    int d = l0 >> 3, e0 = l0 & 7;              // e0 in {0,4}
    sg[(e0 + 0) * DDIM + d] = v.x;
    sg[(e0 + 1) * DDIM + d] = v.y;
    sg[(e0 + 2) * DDIM + d] = v.z;
    sg[(e0 + 3) * DDIM + d] = v.w;
  }
  __syncthreads();
  int wave = t >> 6, lane = t & 63;
  int tok0 = blockIdx.x * 8 + wave * 2;        // 8 tokens per block, 2 per wave
#pragma unroll
  for (int tk = 0; tk < 2; ++tk) {
    int tok = tok0 + tk;
    float p[NEXP];
#pragma unroll
    for (int e = 0; e < NEXP; e++) p[e] = 0.f;
#pragma unroll
    for (int c = 0; c < 4; c++) {
      int d = c * 256 + lane * 4;
      float4 xv = *(const float4*)&x[(size_t)tok * DDIM + d];
      short4v sv;                              // fused xb write (each elem once)
      sv[0] = f2bf(xv.x); sv[1] = f2bf(xv.y); sv[2] = f2bf(xv.z); sv[3] = f2bf(xv.w);
      *(short4v*)&xb[(size_t)tok * DDIM + d] = sv;
#pragma unroll
      for (int e = 0; e < NEXP; e++) {
        float4 g = *(const float4*)&sg[e * DDIM + d];
        p[e] += xv.x * g.x + xv.y * g.y + xv.z * g.z + xv.w * g.w;
      }
    }
#pragma unroll
    for (int off = 32; off; off >>= 1)
#pragma unroll
      for (int e = 0; e < NEXP; e++) p[e] += __shfl_xor(p[e], off);
    if (lane == 0) {
      float l[NEXP];
#pragma unroll
      for (int e = 0; e < NEXP; e++) l[e] = p[e] + gb[e];
      int i0 = 0;
#pragma unroll
      for (int e = 1; e < NEXP; e++) if (l[e] > l[i0]) i0 = e;   // first-max (jax tie-break)
      int i1 = (i0 == 0) ? 1 : 0;
#pragma unroll
      for (int e = 0; e < NEXP; e++) if (e != i0 && l[e] > l[i1]) i1 = e;
      float ex = expf(l[i1] - l[i0]);
      float w0 = 1.f / (1.f + ex);
      toke[tok] = make_int2(i0, i1);
      tokw[tok] = make_float2(w0, 1.f - w0);
      atomicAdd(&cnt[i0], 1);
      atomicAdd(&cnt[i1], 1);
    }
  }
}

// ---------------- routing plan (64 threads) ----------------
__global__ void k_plan(const int* __restrict__ cnt, int* __restrict__ pbase,
                       int* __restrict__ texp) {
  int t = threadIdx.x;
  int b[NEXP + 1]; b[0] = 0;
#pragma unroll
  for (int e = 0; e < NEXP; e++) {
    int pc = (cnt[e] + BM - 1) & ~(BM - 1);
    b[e + 1] = b[e] + pc;
  }
  if (t < NEXP) pbase[t] = b[t];
  for (int i = t; i < MAXTILES; i += 64) {
    int r0 = i * BM, ee = -1;
#pragma unroll
    for (int e = 0; e < NEXP; e++) if (r0 >= b[e] && r0 < b[e + 1]) ee = e;
    texp[i] = ee;
  }
}

__global__ __launch_bounds__(256) void k_scatter(const int2* __restrict__ toke,
    const float2* __restrict__ tokw, const int* __restrict__ pbase,
    int* __restrict__ fill, int* __restrict__ rtok, float* __restrict__ rwgt) {
  int tok = blockIdx.x * 256 + threadIdx.x;
  if (tok >= T_TOK) return;
  int2 te = toke[tok];
  float2 tw = tokw[tok];
  int s0 = atomicAdd(&fill[te.x], 1);
  rtok[pbase[te.x] + s0] = tok; rwgt[pbase[te.x] + s0] = tw.x;
  int s1 = atomicAdd(&fill[te.y], 1);
  rtok[pbase[te.y] + s1] = tok; rwgt[pbase[te.y] + s1] = tw.y;
}

// ============== 128x128-tile grouped GEMM, 4 waves (2M x 2N, 64x64/wave) ==========
// Round-10 proven config: 4 blocks/CU (acc[4][4]=64 AGPR, launch_bounds(256,4),
// 32 KiB LDS), XOR-8 swizzle (0 conflicts), STAGE->vmcnt(0)->barrier->MFMA->barrier,
// grid x = n0 (fast dim: A-panel sharers temporally adjacent -> LLC hits).

#define STG(ko) { \
  gld16(sA[0] + (ko), &AL[(0 * 32 + wid * 8) * BK]); \
  gld16(sA[1] + (ko), &AL[(1 * 32 + wid * 8) * BK]); \
  gld16(sA[2] + (ko), &AL[(2 * 32 + wid * 8) * BK]); \
  gld16(sA[3] + (ko), &AL[(3 * 32 + wid * 8) * BK]); \
  gld16(sB[0] + (ko), &BL[(0 * 32 + wid * 8) * BK]); \
  gld16(sB[1] + (ko), &BL[(1 * 32 + wid * 8) * BK]); \
  gld16(sB[2] + (ko), &BL[(2 * 32 + wid * 8) * BK]); \
  gld16(sB[3] + (ko), &BL[(3 * 32 + wid * 8) * BK]); }

#define MFMA_TILE { \
  __builtin_amdgcn_s_setprio(1); \
  _Pragma("unroll") \
  for (int s = 0; s < 2; ++s) { \
    int xo = ((s * 4 + kg) ^ x7) << 3; \
    short8 af[4], bg[4]; \
    _Pragma("unroll") \
    for (int i = 0; i < 4; i++) af[i] = *(short8*)&AL[(wm + i * 16 + lr) * BK + xo]; \
    _Pragma("unroll") \
    for (int j = 0; j < 4; j++) bg[j] = *(short8*)&BL[(wn + j * 16 + lr) * BK + xo]; \
    _Pragma("unroll") \
    for (int i = 0; i < 4; i++) \
    _Pragma("unroll") \
    for (int j = 0; j < 4; j++) \
      acc[i][j] = __builtin_amdgcn_mfma_f32_16x16x32_bf16(af[i], bg[j], acc[i][j], 0, 0, 0); \
  } \
  __builtin_amdgcn_s_setprio(0); }

#define GEMM_LOOP(NKv) \
  for (int kt = 0; kt < (NKv); ++kt) { \
    STG(kt * BK); \
    asm volatile("s_waitcnt vmcnt(0)" ::: "memory"); \
    __syncthreads(); \
    MFMA_TILE; \
    __syncthreads(); \
  }

// ---------------- stage 1: h = gelu(x @ w1[e] + b1[e]) ----------------
// grid (HDIM/128 = 32, nt), 256 threads. w1t = [e][n(H)][k(D)] bf16.
__global__ __launch_bounds__(256, 4) void k_ffn1(const short* __restrict__ xb,
    const short* __restrict__ w1t, const float* __restrict__ b1,
    const int* __restrict__ rtok, const int* __restrict__ texp,
    int tile_base, short* __restrict__ hbuf) {
  int tl = blockIdx.y;
  int tm = tile_base + tl;
  int e = texp[tm];
  if (e < 0) return;
  int n0 = blockIdx.x * BN;
  const short* W = w1t + (size_t)e * HDIM * DDIM;
  __shared__ short LDSBUF[2 * BM * BK];   // 32 KiB; AL|BL during loop, staging after
  short* AL = LDSBUF;
  short* BL = LDSBUF + BM * BK;
  int t = threadIdx.x, wid = t >> 6, lane = t & 63;
  int sr8 = lane >> 3, slot = lane & 7;
  int swz = (slot ^ sr8) * 8;
  const short* sA[4]; const short* sB[4];
#pragma unroll
  for (int i = 0; i < 4; i++) {
    int r = i * 32 + wid * 8 + sr8;
    int tok = rtok[tm * BM + r]; if (tok < 0) tok = 0;   // pads read row0 (dropped in ffn2)
    sA[i] = xb + (size_t)tok * DDIM + swz;
    sB[i] = W + (size_t)(n0 + r) * DDIM + swz;
  }

  f32x4 acc[4][4];
#pragma unroll
  for (int i = 0; i < 4; i++)
#pragma unroll
    for (int j = 0; j < 4; j++) acc[i][j] = (f32x4){0.f, 0.f, 0.f, 0.f};

  int wm = (wid >> 1) * 64, wn = (wid & 1) * 64;
  int lr = lane & 15, kg = lane >> 4, x7 = lr & 7;

  GEMM_LOOP(DDIM / BK)   // 16

  // LDS-staged vectorized epilogue (wave-private [32][68] region, no barriers)
  short* SB = LDSBUF + wid * (32 * 68);
#pragma unroll
  for (int p = 0; p < 2; ++p) {
#pragma unroll
    for (int i2 = 0; i2 < 2; ++i2) {
      int i = p * 2 + i2;
#pragma unroll
      for (int j = 0; j < 4; ++j) {
        int col = j * 16 + lr;
        float bias = b1[e * HDIM + n0 + wn + col];
#pragma unroll
        for (int r = 0; r < 4; ++r) {
          float v = acc[i][j][r] + bias;
          v = 0.5f * v * (1.f + erff(v * 0.70710678118f));
          SB[(i2 * 16 + kg * 4 + r) * 68 + col] = f2bf(v);
        }
      }
    }
    int lrow = lane >> 1, c0 = (lane & 1) * 32;
    size_t grow = (size_t)(tl * BM + wm + p * 32 + lrow);
#pragma unroll
    for (int s = 0; s < 4; ++s) {
      short8 v = *(short8*)&SB[lrow * 68 + c0 + s * 8];
      *(short8*)&hbuf[grow * HDIM + n0 + wn + c0 + s * 8] = v;
    }
  }
}

// ---------------- stage 2: out[tok] += wgt * (h @ w2[e] + b2[e]) ----------------
// grid (DDIM/128 = 8, KS2, nt), 256 threads. w2t = [e][n(D)][k(H)] bf16. Split-K over H.
__global__ __launch_bounds__(256, 4) void k_ffn2(const short* __restrict__ hbuf,
    const short* __restrict__ w2t, const float* __restrict__ b2,
    const int* __restrict__ rtok, const float* __restrict__ rwgt,
    const int* __restrict__ texp, int tile_base, float* __restrict__ out) {
  int tl = blockIdx.z;
  int tm = tile_base + tl;
  int e = texp[tm];
  if (e < 0) return;
  int kc = blockIdx.y;
  int n0 = blockIdx.x * BN;
  const short* W = w2t + (size_t)e * DDIM * HDIM;
  __shared__ short LDSBUF[2 * BM * BK];
  short* AL = LDSBUF;
  short* BL = LDSBUF + BM * BK;
  int t = threadIdx.x, wid = t >> 6, lane = t & 63;
  int sr8 = lane >> 3, slot = lane & 7;
  int swz = (slot ^ sr8) * 8;
  const int NK = HDIM / BK / KS2;            // 32
  int kbase = kc * NK * BK;
  const short* sA[4]; const short* sB[4];
#pragma unroll
  for (int i = 0; i < 4; i++) {
    int r = i * 32 + wid * 8 + sr8;
    sA[i] = hbuf + (size_t)(tl * BM + r) * HDIM + kbase + swz;
    sB[i] = W + (size_t)(n0 + r) * HDIM + kbase + swz;
  }

  f32x4 acc[4][4];
#pragma unroll
  for (int i = 0; i < 4; i++)
#pragma unroll
    for (int j = 0; j < 4; j++) acc[i][j] = (f32x4){0.f, 0.f, 0.f, 0.f};

  int wm = (wid >> 1) * 64, wn = (wid & 1) * 64;
  int lr = lane & 15, kg = lane >> 4, x7 = lr & 7;

  GEMM_LOOP(NK)

#pragma unroll
  for (int j = 0; j < 4; j++) {
    int gcol = n0 + wn + j * 16 + lr;
    float bias = (kc == 0) ? b2[e * DDIM + gcol] : 0.f;
#pragma unroll
    for (int i = 0; i < 4; i++) {
      int rl = wm + i * 16 + kg * 4;
#pragma unroll
      for (int r = 0; r < 4; r++) {
        int grow = tm * BM + rl + r;
        int tok = rtok[grow];
        if (tok >= 0) {
          float v = (acc[i][j][r] + bias) * rwgt[grow];
          atomicAdd(&out[(size_t)tok * DDIM + gcol], v);
        }
      }
    }
  }
}

extern "C" void kernel_launch(void* const* d_in, const int* in_sizes, int n_in,
                              void* d_out, int out_size, void* d_ws, size_t ws_size,
                              hipStream_t stream) {
  const float* x  = (const float*)d_in[0];
  const float* gw = (const float*)d_in[1];
  const float* gb = (const float*)d_in[2];
  const float* w1 = (const float*)d_in[3];
  const float* b1 = (const float*)d_in[4];
  const float* w2 = (const float*)d_in[5];
  const float* b2 = (const float*)d_in[6];
  float* out = (float*)d_out;
  char* ws = (char*)d_ws;

  // ws layout: 1MB header | w1t 67.1MB | w2t 67.1MB | xb 16.8MB | hbuf (chunked)
  int*    cnt   = (int*)(ws + 0);
  int*    fill  = (int*)(ws + 32);
  int*    pbase = (int*)(ws + 64);
  int*    texp  = (int*)(ws + 128);
  int*    rtok  = (int*)(ws + 1024);
  float*  rwgt  = (float*)(ws + 1024 + (size_t)MAXROWS * 4);
  int2*   toke  = (int2*)(ws + 1024 + (size_t)MAXROWS * 8);
  float2* tokw  = (float2*)(ws + 1024 + (size_t)MAXROWS * 8 + (size_t)T_TOK * 8);
  size_t wbytes = (size_t)NEXP * DDIM * HDIM * 2;
  short*  w1t   = (short*)(ws + (1 << 20));
  short*  w2t   = (short*)(ws + (1 << 20) + wbytes);
  short*  xb    = (short*)(ws + (1 << 20) + 2 * wbytes);
  size_t hoff   = (1 << 20) + 2 * wbytes + (size_t)T_TOK * DDIM * 2;
  short*  hbuf  = (short*)(ws + hoff);

  size_t hcap = ws_size > hoff ? ws_size - hoff : 0;
  int tpc = (int)(hcap / ((size_t)BM * HDIM * 2));   // 1MB per tile of h
  if (tpc < 1) return;
  if (tpc > MAXTILES) tpc = MAXTILES;

  hipMemsetAsync(d_out, 0, (size_t)T_TOK * DDIM * 4, stream);
  hipMemsetAsync(ws, 0, 128, stream);
  hipMemsetAsync(rtok, 0xFF, (size_t)MAXROWS * 4, stream);

  k_tr<<<dim3(HDIM / 64, DDIM / 64, NEXP), 256, 0, stream>>>(w1, w1t, DDIM, HDIM);
  k_tr<<<dim3(DDIM / 64, HDIM / 64, NEXP), 256, 0, stream>>>(w2, w2t, HDIM, DDIM);

  k_gate<<<T_TOK / 8, 256, 0, stream>>>(x, gw, gb, toke, tokw, cnt, xb);
  k_plan<<<1, 64, 0, stream>>>(cnt, pbase, texp);
  k_scatter<<<T_TOK / 256, 256, 0, stream>>>(toke, tokw, pbase, fill, rtok, rwgt);

  for (int base = 0; base < MAXTILES; base += tpc) {
    int nt = MAXTILES - base;
    if (nt > tpc) nt = tpc;
    k_ffn1<<<dim3(HDIM / BN, nt), 256, 0, stream>>>(xb, w1t, b1, rtok, texp, base, hbuf);
    k_ffn2<<<dim3(DDIM / BN, KS2, nt), 256, 0, stream>>>(hbuf, w2t, b2, rtok, rwgt,
                                                         texp, base, out);
  }
}